// Round 9
// baseline (278.665 us; speedup 1.0000x reference)
//
#include <hip/hip_runtime.h>
#include <math.h>

// Problem constants
#define NN 4096      // nodes
#define NE 65536     // edges
#define LL 64        // latent dims
#define KK 256       // kernel dims
#define ED 6         // edge dims
#define MAXSUPER 6144   // sum ceil(deg/32) <= (65536 + 31*4096)/32 = 6016

typedef __bf16 bf16_t;
typedef __attribute__((ext_vector_type(4))) __bf16 bf16x4;
typedef __attribute__((ext_vector_type(8))) __bf16 bf16x8;
typedef __attribute__((ext_vector_type(4))) float f32x4;
typedef __attribute__((ext_vector_type(16))) float f32x16;

// workspace layout (bytes)
#define OFF_CNT    ((size_t)0)           // 16384
#define OFF_DESC   ((size_t)16384)       // 8192*16 = 131072 (>= MAXSUPER*16)
#define OFF_AGG0   ((size_t)147456)      // 1 MB
#define OFF_AGG1   ((size_t)1196032)     // 1 MB
#define ZERO_BYTES ((size_t)2244608)
#define OFF_CURSOR ((size_t)2244608)     // 16384
#define OFF_SORTED ((size_t)2260992)     // 65536*8 = 524288
#define OFF_W2R    ((size_t)2785280)     // 131072
#define OFF_W3RR   ((size_t)2916352)     // 2097152
#define OFF_Q0     ((size_t)5013504)     // 1 MB
#define OFF_Q1     ((size_t)6062080)     // 1 MB
#define OFF_X1F    ((size_t)7110656)     // 1 MB
#define OFF_X0BF   ((size_t)8159232)     // 512 KB
#define OFF_X1BF   ((size_t)8683520)     // 512 KB
#define OFF_H      ((size_t)9207808)     // 32 MB; a1 ALIASES h (in-place mlp2)
#define OFF_P      ((size_t)42762240)    // 128 MB; no aliases

__device__ __forceinline__ float gelu_f(float x) {
    return 0.5f * x * (1.0f + erff(x * 0.7071067811865476f));
}
__device__ __forceinline__ bf16_t f2bf(float x) { return (bf16_t)x; }

// ---- 1. histogram of src degrees ----
__global__ void k_hist(const int* __restrict__ ei, int* __restrict__ cnt) {
    int e = blockIdx.x * 256 + threadIdx.x;
    atomicAdd(&cnt[ei[e]], 1);
}

// ---- 2. single-block scan: cursors + 32-edge superchunk descriptors ----
__global__ void k_scan(const int* __restrict__ cnt, int* __restrict__ cursor,
                       int4* __restrict__ descs) {
    __shared__ int pd[1024], pc[1024];
    int t = threadIdx.x;
    int deg[4]; int sd = 0, sc = 0;
#pragma unroll
    for (int j = 0; j < 4; j++) {
        deg[j] = cnt[t * 4 + j];
        sd += deg[j];
        sc += (deg[j] + 31) >> 5;
    }
    pd[t] = sd; pc[t] = sc;
    __syncthreads();
    for (int off = 1; off < 1024; off <<= 1) {
        int vd = 0, vc = 0;
        if (t >= off) { vd = pd[t - off]; vc = pc[t - off]; }
        __syncthreads();
        pd[t] += vd; pc[t] += vc;
        __syncthreads();
    }
    int rd = (t > 0) ? pd[t - 1] : 0;
    int rc = (t > 0) ? pc[t - 1] : 0;
    for (int j = 0; j < 4; j++) {
        int v = t * 4 + j, d = deg[j];
        cursor[v] = rd;
        int nch = (d + 31) >> 5;
        for (int c = 0; c < nch; c++) {
            int rem = d - c * 32;
            descs[rc + c] = make_int4(v, rd + c * 32, rem < 32 ? rem : 32, 0);
        }
        rc += nch; rd += d;
    }
}

// ---- 3. fused independent pre-work ----
// blocks [0,256): scatter | [256,512): prep W3rr | [512,768): prep W2r
// [768,1792): mlp1 | [1792,2816): node0
__global__ void __launch_bounds__(256) k_fuse3(
        const int* __restrict__ ei, int* __restrict__ cursor, int2* __restrict__ sorted,
        const float* __restrict__ W3, bf16_t* __restrict__ W3rr,
        const float* __restrict__ W2, bf16_t* __restrict__ W2r,
        const float* __restrict__ attr, const float* __restrict__ W1,
        const float* __restrict__ b1, bf16_t* __restrict__ a1,
        const float* __restrict__ x, const float* __restrict__ b3,
        bf16_t* __restrict__ xbf, float* __restrict__ Q) {
    __shared__ float smem[4096];
    int bid = blockIdx.x, tid = threadIdx.x;
    if (bid < 256) {
        // ---- scatter ----
        int e = bid * 256 + tid;
        int s = ei[e], d = ei[NE + e];
        int pos = atomicAdd(&cursor[s], 1);
        sorted[pos] = make_int2(e, d);
    } else if (bid < 512) {
        // ---- prep W3 (coalesced, one k-slice per block) ----
        // s(k,o) = ((k>>4)*2+(o>>5))*512 + (((k>>3)&1)*32+(o&31))*8 + (k&7)
        // f(s,i) = (s>>4)*1024 + (i>>5)*512 + ((i>>3)&3)*128 + (s&15)*8 + (i&7)
        int k0 = bid - 256;
        for (int idx = tid; idx < 4096; idx += 256)
            smem[idx] = W3[(size_t)k0 * 4096 + idx];
        __syncthreads();
        int sbase = (2 * (k0 >> 4)) * 512 + (((k0 >> 3) & 1) * 32) * 8 + (k0 & 7);
#pragma unroll
        for (int m = 0; m < 2; m++) {
            int w = m * 256 + tid;       // 0..511
            int o = w >> 3, ib = w & 7;
            int s = sbase + (o >> 5) * 512 + (o & 31) * 8;
            int f = (s >> 4) * 1024 + (ib >> 2) * 512 + (ib & 3) * 128 + (s & 15) * 8;
            bf16x8 pk;
#pragma unroll
            for (int j = 0; j < 8; j++) pk[j] = f2bf(smem[(ib * 8 + j) * 64 + o]);
            *(bf16x8*)(W3rr + f) = pk;
        }
    } else if (bid < 768) {
        // ---- prep W2r ----
        int t = (bid - 512) * 256 + tid;
        int kk = t >> 13, nn = (t >> 9) & 15, lane = (t >> 3) & 63, j = t & 7;
        int k = kk * 32 + (lane >> 4) * 8 + j;
        int n = nn * 16 + (lane & 15);
        W2r[t] = f2bf(W2[k * 256 + n]);
    } else if (bid < 1792) {
        // ---- mlp1 ----
        float* sa = smem;
        int e0 = (bid - 768) * 64;
        for (int i = tid; i < 64 * ED; i += 256) sa[i] = attr[(size_t)e0 * ED + i];
        int col4 = (tid & 63) * 4;
        float w[ED][4], bb[4];
#pragma unroll
        for (int j = 0; j < ED; j++)
#pragma unroll
            for (int c = 0; c < 4; c++) w[j][c] = W1[j * 256 + col4 + c];
#pragma unroll
        for (int c = 0; c < 4; c++) bb[c] = b1[col4 + c];
        __syncthreads();
        int esub = tid >> 6;
#pragma unroll 1
        for (int eg = 0; eg < 16; eg++) {
            int el = eg * 4 + esub;
            float av[ED];
#pragma unroll
            for (int j = 0; j < ED; j++) av[j] = sa[el * ED + j];
            bf16x4 ov;
#pragma unroll
            for (int c = 0; c < 4; c++) {
                float acc = bb[c];
#pragma unroll
                for (int j = 0; j < ED; j++) acc += av[j] * w[j][c];
                ov[c] = f2bf(gelu_f(acc));
            }
            *(bf16x4*)(a1 + (size_t)(e0 + el) * 256 + col4) = ov;
        }
    } else {
        // ---- node0: xbf + Q, 4 nodes/block ----
        int v = (bid - 1792) * 4 + (tid >> 6);
        int o = tid & 63;
        float xv = x[v * 64 + o];
        smem[tid] = xv;
        xbf[v * 64 + o] = f2bf(xv);
        __syncthreads();
        const float* sx = smem + (tid >> 6) * 64;
        float q = 0.0f;
#pragma unroll 8
        for (int i = 0; i < 64; i++) q += sx[i] * b3[i * 64 + o];
        Q[v * 64 + o] = q;
    }
}

// ---- P-GEMM body: LDS-staged W3 frags + block-shared two-phase transpose ----
// R5-R8 lesson: the allocator refuses to keep b[16][2] (128 VGPR) resident;
// every rt re-fetched 32 KB from L2 (~200-cyc serial stalls, 3.7 TB/s
// plateau). Fix: W3 strip frags live in LDS (32 KB, CONTIGUOUS in W3rr ->
// linear block copy), read via ds_read_b128 per nn. Transpose buffer is
// block-shared 64x132 used in two column phases so total LDS = 49.6 KB
// (3 blocks/CU). VGPR drops to ~60 -> real occupancy hides LDS latency.
__device__ __forceinline__ void pgemm_body(const bf16_t* __restrict__ xbf,
                                           const bf16_t* __restrict__ W3rr,
                                           bf16_t* __restrict__ P,
                                           bf16_t* __restrict__ sW,   // 16384 elems
                                           bf16_t* __restrict__ sT,   // 8448 elems (64x132)
                                           int strip, int rg) {
    int tid = threadIdx.x;
    int wave = tid >> 6, lane = tid & 63;
    int col = lane & 15, quad = lane >> 4;
    // stage strip's 32 fragments (contiguous 32 KB) into LDS
    const bf16x8* gsrc = (const bf16x8*)(W3rr + (size_t)strip * 16384);
    bf16x8* ldst = (bf16x8*)sW;
#pragma unroll
    for (int it = 0; it < 8; it++)
        ldst[it * 256 + tid] = gsrc[it * 256 + tid];
    __syncthreads();
#pragma unroll 1
    for (int rt = 0; rt < 4; rt++) {
        int rowblk = rg * 256 + rt * 64;           // 64 contiguous rows this rt
        int rowbase = rowblk + wave * 16;          // this wave's 16 rows
        const bf16_t* arow = xbf + (size_t)(rowbase + col) * 64;
        bf16x8 a0 = *(const bf16x8*)(arow + quad * 8);
        bf16x8 a1v = *(const bf16x8*)(arow + 32 + quad * 8);
#pragma unroll 1
        for (int phase = 0; phase < 2; phase++) {
#pragma unroll
            for (int nn = 0; nn < 8; nn++) {
                int fn = phase * 8 + nn;
                bf16x8 b0 = *(const bf16x8*)(sW + (fn * 2 + 0) * 512 + lane * 8);
                bf16x8 b1 = *(const bf16x8*)(sW + (fn * 2 + 1) * 512 + lane * 8);
                f32x4 acc;
#pragma unroll
                for (int r = 0; r < 4; r++) acc[r] = 0.0f;
                // swapped: A = W3 frag, B = x frag -> D[s-local][node]
                acc = __builtin_amdgcn_mfma_f32_16x16x32_bf16(b0, a0, acc, 0, 0, 0);
                acc = __builtin_amdgcn_mfma_f32_16x16x32_bf16(b1, a1v, acc, 0, 0, 0);
                bf16x4 pk;
#pragma unroll
                for (int r = 0; r < 4; r++) pk[r] = f2bf(acc[r]);
                *(bf16x4*)(sT + (wave * 16 + col) * 132 + nn * 16 + quad * 4) = pk;
            }
            __syncthreads();
            // cooperative store: 64 rows x 128 cols, full-line bursts
#pragma unroll
            for (int it = 0; it < 4; it++) {
                int c = it * 256 + tid;        // 0..1023
                int row = c >> 4;              // 0..63
                int cp = (c & 15) * 8;         // 0..120
                bf16x8 vd = *(const bf16x8*)(sT + row * 132 + cp);
                *(bf16x8*)(P + (size_t)(rowblk + row) * 16384 +
                           strip * 256 + phase * 128 + cp) = vd;
            }
            __syncthreads();
        }
    }
}

// ---- 4. fused: P-GEMM (blocks 0..1023) + MLP layer 2 (blocks 1024..1535) ----
// NOTE: a1 aliases h (in-place slab transform). Safe: every h-store in a wave
// depends via wave-synchronous MFMA on ALL that wave's a1-loads (rows
// [base,base+32)), and waves touch disjoint row slabs. P has no aliases.
__global__ void __launch_bounds__(256) k_fuse4(const bf16_t* __restrict__ xbf,
                                               const bf16_t* __restrict__ W3rr,
                                               bf16_t* __restrict__ P,
                                               const bf16_t* __restrict__ a1,
                                               const bf16_t* __restrict__ W2r,
                                               const float* __restrict__ b2,
                                               bf16_t* __restrict__ h) {
    __shared__ bf16_t sW[16384];   // pgemm: W3 frags | mlp2: W2 tile
    __shared__ bf16_t sT[8448];    // pgemm transpose buffer (64x132)
    if (blockIdx.x < 1024) {
        pgemm_body(xbf, W3rr, P, sW, sT, blockIdx.x & 63, blockIdx.x >> 6);
    } else {
        // ---- MLP layer 2: h = gelu(a1 @ W2 + b2), LDS-staged, in-place ----
        int tid = threadIdx.x;
        int wave = tid >> 6, lane = tid & 63, col = lane & 15, quad = lane >> 4;
        int base = (blockIdx.x - 1024) * 128 + wave * 32;
        bf16x8 a[2][8];
#pragma unroll
        for (int t = 0; t < 2; t++) {
            const bf16_t* arow = a1 + (size_t)(base + t * 16 + col) * 256;
#pragma unroll
            for (int kk = 0; kk < 8; kk++)
                a[t][kk] = *(const bf16x8*)(arow + kk * 32 + quad * 8);
        }
#pragma unroll 1
        for (int p = 0; p < 4; p++) {
#pragma unroll
            for (int it = 0; it < 8; it++) {
                int c = it * 256 + tid;
                int fl = c >> 6;
                int e = (c & 63) * 8;
                int kk = fl >> 2, nnl = fl & 3;
                *(bf16x8*)(sW + fl * 512 + e) =
                    *(const bf16x8*)(W2r + (size_t)(kk * 16 + p * 4 + nnl) * 512 + e);
            }
            __syncthreads();
#pragma unroll
            for (int nnl = 0; nnl < 4; nnl++) {
                f32x4 acc0, acc1;
#pragma unroll
                for (int r = 0; r < 4; r++) { acc0[r] = 0.0f; acc1[r] = 0.0f; }
#pragma unroll
                for (int kk = 0; kk < 8; kk++) {
                    bf16x8 b = *(const bf16x8*)(sW + (kk * 4 + nnl) * 512 + lane * 8);
                    acc0 = __builtin_amdgcn_mfma_f32_16x16x32_bf16(a[0][kk], b, acc0, 0, 0, 0);
                    acc1 = __builtin_amdgcn_mfma_f32_16x16x32_bf16(a[1][kk], b, acc1, 0, 0, 0);
                }
                int ncol = (p * 4 + nnl) * 16 + col;
                float bv = b2[ncol];
#pragma unroll
                for (int r = 0; r < 4; r++) {
                    int row0 = base + quad * 4 + r;
                    h[(size_t)row0 * 256 + ncol] = f2bf(gelu_f(acc0[r] + bv));
                    h[(size_t)(row0 + 16) * 256 + ncol] = f2bf(gelu_f(acc1[r] + bv));
                }
            }
            __syncthreads();
        }
    }
}

// ---- standalone P-GEMM for conv 1 ----
__global__ void __launch_bounds__(256) k_pgemm(const bf16_t* __restrict__ xbf,
                                               const bf16_t* __restrict__ W3rr,
                                               bf16_t* __restrict__ P) {
    __shared__ bf16_t sW[16384];
    __shared__ bf16_t sT[8448];
    pgemm_body(xbf, W3rr, P, sW, sT, blockIdx.x & 63, blockIdx.x >> 6);
}

// ---- aggregation: 32-edge superchunk (same src), 32x32x16 MFMA ----
// A: A[m=lane&31][k=(lane>>5)*8+j]; C/D: col=lane&31, row=(reg&3)+8*(reg>>2)+4*(lane>>5)
__global__ void __launch_bounds__(256) k_agg(const int4* __restrict__ descs,
                                             const int2* __restrict__ sorted,
                                             const bf16_t* __restrict__ h,
                                             const bf16_t* __restrict__ P,
                                             const float* __restrict__ Q,
                                             float* __restrict__ agg) {
    int chunk = blockIdx.x * 4 + (threadIdx.x >> 6);
    int lane = threadIdx.x & 63;
    int row = lane & 31, khalf = lane >> 5;
    int4 d = descs[chunk];
    int v = d.x, base = d.y, cnt = d.z;
    if (cnt == 0) return;
    bool valid = (row < cnt);
    int2 ed = sorted[base + (valid ? row : 0)];
    int eid = ed.x, dst = ed.y;

    bf16x8 zero;
#pragma unroll
    for (int i = 0; i < 8; i++) zero[i] = (bf16_t)0.0f;

    bf16x8 a[16];
    const bf16_t* hrow = h + (size_t)eid * 256;
#pragma unroll
    for (int kt = 0; kt < 16; kt++) {
        bf16x8 t = *(const bf16x8*)(hrow + kt * 16 + khalf * 8);
        a[kt] = valid ? t : zero;
    }
    const bf16_t* Pv = P + (size_t)v * 16384;
    f32x16 acc0, acc1;
#pragma unroll
    for (int r = 0; r < 16; r++) { acc0[r] = 0.0f; acc1[r] = 0.0f; }
#pragma unroll
    for (int kt = 0; kt < 16; kt++) {
        bf16x8 b0 = *(const bf16x8*)(Pv + (size_t)(kt * 2 + 0) * 512 + lane * 8);
        bf16x8 b1 = *(const bf16x8*)(Pv + (size_t)(kt * 2 + 1) * 512 + lane * 8);
        acc0 = __builtin_amdgcn_mfma_f32_32x32x16_bf16(a[kt], b0, acc0, 0, 0, 0);
        acc1 = __builtin_amdgcn_mfma_f32_32x32x16_bf16(a[kt], b1, acc1, 0, 0, 0);
    }
    float q0 = Q[v * 64 + row];
    float q1 = Q[v * 64 + 32 + row];
#pragma unroll
    for (int r = 0; r < 16; r++) {
        int mm = (r & 3) + 8 * (r >> 2) + 4 * khalf;
        int de = __shfl(dst, mm, 64);
        if (mm < cnt) {
            atomicAdd(&agg[(size_t)de * 64 + row], acc0[r] + q0);
            atomicAdd(&agg[(size_t)de * 64 + 32 + row], acc1[r] + q1);
        }
    }
}

// ---- combine after conv0: x1 = gelu(agg + x@Wroot + bias); also x1bf, Q1 ----
__global__ void k_combine1(const float* __restrict__ x, const float* __restrict__ agg,
                           const float* __restrict__ Wroot, const float* __restrict__ bias,
                           const float* __restrict__ b3, float* __restrict__ x1,
                           bf16_t* __restrict__ x1bf, float* __restrict__ Q1) {
    __shared__ float sx[64], sy[64];
    int v = blockIdx.x, o = threadIdx.x;
    sx[o] = x[v * 64 + o];
    __syncthreads();
    float acc = agg[v * 64 + o] + bias[o];
#pragma unroll 8
    for (int i = 0; i < 64; i++) acc += sx[i] * Wroot[i * 64 + o];
    acc = gelu_f(acc);
    x1[v * 64 + o] = acc;
    x1bf[v * 64 + o] = f2bf(acc);
    sy[o] = acc;
    __syncthreads();
    float q = 0.0f;
#pragma unroll 8
    for (int i = 0; i < 64; i++) q += sy[i] * b3[i * 64 + o];
    Q1[v * 64 + o] = q;
}

// ---- final combine: out = agg + x1@Wroot + bias ----
__global__ void k_combine2(const float* __restrict__ x1, const float* __restrict__ agg,
                           const float* __restrict__ Wroot, const float* __restrict__ bias,
                           float* __restrict__ out) {
    __shared__ float sx[64];
    int v = blockIdx.x, o = threadIdx.x;
    sx[o] = x1[v * 64 + o];
    __syncthreads();
    float acc = agg[v * 64 + o] + bias[o];
#pragma unroll 8
    for (int i = 0; i < 64; i++) acc += sx[i] * Wroot[i * 64 + o];
    out[v * 64 + o] = acc;
}

extern "C" void kernel_launch(void* const* d_in, const int* in_sizes, int n_in,
                              void* d_out, int out_size, void* d_ws, size_t ws_size,
                              hipStream_t stream) {
    const float* nodes = (const float*)d_in[0];
    const int*   ei    = (const int*)d_in[1];
    const float* attr  = (const float*)d_in[2];
    const float* W1    = (const float*)d_in[3];
    const float* b1    = (const float*)d_in[4];
    const float* W2    = (const float*)d_in[5];
    const float* b2    = (const float*)d_in[6];
    const float* W3    = (const float*)d_in[7];
    const float* b3    = (const float*)d_in[8];
    const float* Wroot = (const float*)d_in[9];
    const float* bias  = (const float*)d_in[10];
    float* out = (float*)d_out;
    char* ws = (char*)d_ws;

    int*    cnt    = (int*)(ws + OFF_CNT);
    int4*   descs  = (int4*)(ws + OFF_DESC);
    float*  agg0   = (float*)(ws + OFF_AGG0);
    float*  agg1   = (float*)(ws + OFF_AGG1);
    int*    cursor = (int*)(ws + OFF_CURSOR);
    int2*   sorted = (int2*)(ws + OFF_SORTED);
    bf16_t* W2r    = (bf16_t*)(ws + OFF_W2R);
    bf16_t* W3rr   = (bf16_t*)(ws + OFF_W3RR);
    float*  Q0     = (float*)(ws + OFF_Q0);
    float*  Q1     = (float*)(ws + OFF_Q1);
    float*  x1f    = (float*)(ws + OFF_X1F);
    bf16_t* x0bf   = (bf16_t*)(ws + OFF_X0BF);
    bf16_t* x1bf   = (bf16_t*)(ws + OFF_X1BF);
    bf16_t* hbuf   = (bf16_t*)(ws + OFF_H);
    bf16_t* a1buf  = (bf16_t*)(ws + OFF_H);  // alias: mlp2 is an in-place slab transform
    bf16_t* Pbuf   = (bf16_t*)(ws + OFF_P);  // no aliases

    hipMemsetAsync(ws, 0, ZERO_BYTES, stream);
    k_hist<<<NE / 256, 256, 0, stream>>>(ei, cnt);
    k_scan<<<1, 1024, 0, stream>>>(cnt, cursor, descs);
    k_fuse3<<<2816, 256, 0, stream>>>(ei, cursor, sorted, W3, W3rr, W2, W2r,
                                      attr, W1, b1, a1buf, nodes, b3, x0bf, Q0);
    k_fuse4<<<1536, 256, 0, stream>>>(x0bf, W3rr, Pbuf, a1buf, W2r, b2, hbuf);
    // conv 0
    k_agg<<<MAXSUPER / 4, 256, 0, stream>>>(descs, sorted, hbuf, Pbuf, Q0, agg0);
    k_combine1<<<NN, 64, 0, stream>>>(nodes, agg0, Wroot, bias, b3, x1f, x1bf, Q1);
    // conv 1
    k_pgemm<<<1024, 256, 0, stream>>>(x1bf, W3rr, Pbuf);
    k_agg<<<MAXSUPER / 4, 256, 0, stream>>>(descs, sorted, hbuf, Pbuf, Q1, agg1);
    k_combine2<<<NN, 64, 0, stream>>>(x1f, agg1, Wroot, bias, out);
}

// Round 10
// 259.615 us; speedup vs baseline: 1.0734x; 1.0734x over previous
//
#include <hip/hip_runtime.h>
#include <math.h>

// Problem constants
#define NN 4096      // nodes
#define NE 65536     // edges
#define LL 64        // latent dims
#define KK 256       // kernel dims
#define ED 6         // edge dims
#define MAXSUPER 6144   // sum ceil(deg/32) <= (65536 + 31*4096)/32 = 6016

typedef __bf16 bf16_t;
typedef __attribute__((ext_vector_type(4))) __bf16 bf16x4;
typedef __attribute__((ext_vector_type(8))) __bf16 bf16x8;
typedef __attribute__((ext_vector_type(4))) float f32x4;
typedef __attribute__((ext_vector_type(16))) float f32x16;

// workspace layout (bytes)
#define OFF_CNT    ((size_t)0)           // 16384
#define OFF_DESC   ((size_t)16384)       // 8192*16 = 131072 (>= MAXSUPER*16)
#define OFF_AGG0   ((size_t)147456)      // 1 MB
#define OFF_AGG1   ((size_t)1196032)     // 1 MB
#define ZERO_BYTES ((size_t)2244608)
#define OFF_CURSOR ((size_t)2244608)     // 16384
#define OFF_SORTED ((size_t)2260992)     // 65536*8 = 524288
#define OFF_W2R    ((size_t)2785280)     // 131072
#define OFF_W3RR   ((size_t)2916352)     // 2097152
#define OFF_Q0     ((size_t)5013504)     // 1 MB
#define OFF_Q1     ((size_t)6062080)     // 1 MB
#define OFF_X1F    ((size_t)7110656)     // 1 MB
#define OFF_X0BF   ((size_t)8159232)     // 512 KB
#define OFF_X1BF   ((size_t)8683520)     // 512 KB
#define OFF_H      ((size_t)9207808)     // 32 MB; a1 ALIASES h (in-place mlp2)
#define OFF_P      ((size_t)42762240)    // 128 MB; no aliases

__device__ __forceinline__ float gelu_f(float x) {
    return 0.5f * x * (1.0f + erff(x * 0.7071067811865476f));
}
__device__ __forceinline__ bf16_t f2bf(float x) { return (bf16_t)x; }

// ---- 1. histogram of src degrees ----
__global__ void k_hist(const int* __restrict__ ei, int* __restrict__ cnt) {
    int e = blockIdx.x * 256 + threadIdx.x;
    atomicAdd(&cnt[ei[e]], 1);
}

// ---- 2. single-block scan: cursors + 32-edge superchunk descriptors ----
__global__ void k_scan(const int* __restrict__ cnt, int* __restrict__ cursor,
                       int4* __restrict__ descs) {
    __shared__ int pd[1024], pc[1024];
    int t = threadIdx.x;
    int deg[4]; int sd = 0, sc = 0;
#pragma unroll
    for (int j = 0; j < 4; j++) {
        deg[j] = cnt[t * 4 + j];
        sd += deg[j];
        sc += (deg[j] + 31) >> 5;
    }
    pd[t] = sd; pc[t] = sc;
    __syncthreads();
    for (int off = 1; off < 1024; off <<= 1) {
        int vd = 0, vc = 0;
        if (t >= off) { vd = pd[t - off]; vc = pc[t - off]; }
        __syncthreads();
        pd[t] += vd; pc[t] += vc;
        __syncthreads();
    }
    int rd = (t > 0) ? pd[t - 1] : 0;
    int rc = (t > 0) ? pc[t - 1] : 0;
    for (int j = 0; j < 4; j++) {
        int v = t * 4 + j, d = deg[j];
        cursor[v] = rd;
        int nch = (d + 31) >> 5;
        for (int c = 0; c < nch; c++) {
            int rem = d - c * 32;
            descs[rc + c] = make_int4(v, rd + c * 32, rem < 32 ? rem : 32, 0);
        }
        rc += nch; rd += d;
    }
}

// ---- 3. fused independent pre-work ----
// blocks [0,256): scatter | [256,512): prep W3rr | [512,768): prep W2r
// [768,1792): mlp1 | [1792,2816): node0
__global__ void __launch_bounds__(256) k_fuse3(
        const int* __restrict__ ei, int* __restrict__ cursor, int2* __restrict__ sorted,
        const float* __restrict__ W3, bf16_t* __restrict__ W3rr,
        const float* __restrict__ W2, bf16_t* __restrict__ W2r,
        const float* __restrict__ attr, const float* __restrict__ W1,
        const float* __restrict__ b1, bf16_t* __restrict__ a1,
        const float* __restrict__ x, const float* __restrict__ b3,
        bf16_t* __restrict__ xbf, float* __restrict__ Q) {
    __shared__ float smem[4096];
    int bid = blockIdx.x, tid = threadIdx.x;
    if (bid < 256) {
        // ---- scatter ----
        int e = bid * 256 + tid;
        int s = ei[e], d = ei[NE + e];
        int pos = atomicAdd(&cursor[s], 1);
        sorted[pos] = make_int2(e, d);
    } else if (bid < 512) {
        // ---- prep W3 (coalesced, one k-slice per block) ----
        // s(k,o) = ((k>>4)*2+(o>>5))*512 + (((k>>3)&1)*32+(o&31))*8 + (k&7)
        // f(s,i) = (s>>4)*1024 + (i>>5)*512 + ((i>>3)&3)*128 + (s&15)*8 + (i&7)
        int k0 = bid - 256;
        for (int idx = tid; idx < 4096; idx += 256)
            smem[idx] = W3[(size_t)k0 * 4096 + idx];
        __syncthreads();
        int sbase = (2 * (k0 >> 4)) * 512 + (((k0 >> 3) & 1) * 32) * 8 + (k0 & 7);
#pragma unroll
        for (int m = 0; m < 2; m++) {
            int w = m * 256 + tid;       // 0..511
            int o = w >> 3, ib = w & 7;
            int s = sbase + (o >> 5) * 512 + (o & 31) * 8;
            int f = (s >> 4) * 1024 + (ib >> 2) * 512 + (ib & 3) * 128 + (s & 15) * 8;
            bf16x8 pk;
#pragma unroll
            for (int j = 0; j < 8; j++) pk[j] = f2bf(smem[(ib * 8 + j) * 64 + o]);
            *(bf16x8*)(W3rr + f) = pk;
        }
    } else if (bid < 768) {
        // ---- prep W2r ----
        int t = (bid - 512) * 256 + tid;
        int kk = t >> 13, nn = (t >> 9) & 15, lane = (t >> 3) & 63, j = t & 7;
        int k = kk * 32 + (lane >> 4) * 8 + j;
        int n = nn * 16 + (lane & 15);
        W2r[t] = f2bf(W2[k * 256 + n]);
    } else if (bid < 1792) {
        // ---- mlp1 ----
        float* sa = smem;
        int e0 = (bid - 768) * 64;
        for (int i = tid; i < 64 * ED; i += 256) sa[i] = attr[(size_t)e0 * ED + i];
        int col4 = (tid & 63) * 4;
        float w[ED][4], bb[4];
#pragma unroll
        for (int j = 0; j < ED; j++)
#pragma unroll
            for (int c = 0; c < 4; c++) w[j][c] = W1[j * 256 + col4 + c];
#pragma unroll
        for (int c = 0; c < 4; c++) bb[c] = b1[col4 + c];
        __syncthreads();
        int esub = tid >> 6;
#pragma unroll 1
        for (int eg = 0; eg < 16; eg++) {
            int el = eg * 4 + esub;
            float av[ED];
#pragma unroll
            for (int j = 0; j < ED; j++) av[j] = sa[el * ED + j];
            bf16x4 ov;
#pragma unroll
            for (int c = 0; c < 4; c++) {
                float acc = bb[c];
#pragma unroll
                for (int j = 0; j < ED; j++) acc += av[j] * w[j][c];
                ov[c] = f2bf(gelu_f(acc));
            }
            *(bf16x4*)(a1 + (size_t)(e0 + el) * 256 + col4) = ov;
        }
    } else {
        // ---- node0: xbf + Q, 4 nodes/block ----
        int v = (bid - 1792) * 4 + (tid >> 6);
        int o = tid & 63;
        float xv = x[v * 64 + o];
        smem[tid] = xv;
        xbf[v * 64 + o] = f2bf(xv);
        __syncthreads();
        const float* sx = smem + (tid >> 6) * 64;
        float q = 0.0f;
#pragma unroll 8
        for (int i = 0; i < 64; i++) q += sx[i] * b3[i * 64 + o];
        Q[v * 64 + o] = q;
    }
}

// ---- P-GEMM body: swapped MFMA + wave LDS transpose + CHANNEL-ROTATED stores ----
// R5-R9 invariant: every store pattern for P plateaus at ~3.2-3.8 TB/s while
// the harness's contiguous fill hits 6.4 — the shared trait is P's 32-KB row
// stride, which maps a block's store burst onto a few HBM channels (at 256B-4KB
// interleave, 32 KB wraps the channel map). Fix: per-node rotation of the 32
// 1-KB chunks, phys_chunk = (chunk + 5*v) & 31 (gcd(5,32)=1 -> consecutive
// rows step the channel index at every interleave granularity). agg applies
// the same bijection on load; contents and fragment order unchanged.
__device__ __forceinline__ void pgemm_body(const bf16_t* __restrict__ xbf,
                                           const bf16_t* __restrict__ W3rr,
                                           bf16_t* __restrict__ P,
                                           bf16_t* __restrict__ sw_wave,
                                           int strip, int rg) {
    int wave = threadIdx.x >> 6, lane = threadIdx.x & 63;
    int col = lane & 15, quad = lane >> 4;
    int half = lane >> 5, l5 = lane & 31;
    bf16_t* sw = sw_wave + wave * 4224;   // 16 rows x 264 elements (8448 B)
    bf16x8 b[16][2];
#pragma unroll
    for (int nn = 0; nn < 16; nn++) {
        int sn = strip * 16 + nn;
#pragma unroll
        for (int ki = 0; ki < 2; ki++)
            b[nn][ki] = *(const bf16x8*)(W3rr + (size_t)(sn * 2 + ki) * 512 + lane * 8);
    }
#pragma unroll 1
    for (int rt = 0; rt < 4; rt++) {
        int rowbase = rg * 256 + wave * 64 + rt * 16;
        const bf16_t* arow = xbf + (size_t)(rowbase + col) * 64;
        bf16x8 a0 = *(const bf16x8*)(arow + quad * 8);
        bf16x8 a1v = *(const bf16x8*)(arow + 32 + quad * 8);
#pragma unroll
        for (int nn = 0; nn < 16; nn++) {
            f32x4 acc;
#pragma unroll
            for (int r = 0; r < 4; r++) acc[r] = 0.0f;
            // swapped: A = W3 frag, B = x frag -> D[s-local][node]
            acc = __builtin_amdgcn_mfma_f32_16x16x32_bf16(b[nn][0], a0, acc, 0, 0, 0);
            acc = __builtin_amdgcn_mfma_f32_16x16x32_bf16(b[nn][1], a1v, acc, 0, 0, 0);
            bf16x4 pk;
#pragma unroll
            for (int r = 0; r < 4; r++) pk[r] = f2bf(acc[r]);
            *(bf16x4*)(sw + col * 264 + nn * 16 + quad * 4) = pk;
        }
        __builtin_amdgcn_wave_barrier();   // pin LDS write->read order
#pragma unroll
        for (int i = 0; i < 8; i++) {
            int r2 = 2 * i + half;   // node-local row 0..15
            int vrow = rowbase + r2;
            bf16x8 vb = *(const bf16x8*)(sw + r2 * 264 + l5 * 8);
            int cphys = ((strip >> 1) + vrow * 5) & 31;   // channel-rotated chunk
            *(bf16x8*)(P + (size_t)vrow * 16384 + cphys * 512 +
                       (strip & 1) * 256 + l5 * 8) = vb;
        }
        __builtin_amdgcn_wave_barrier();   // reads of rt before writes of rt+1
    }
}

// ---- 4. fused: P-GEMM (blocks 0..1023) + MLP layer 2 (blocks 1024..1535) ----
// NOTE: a1 aliases h (in-place slab transform). Safe: every h-store in a wave
// depends via wave-synchronous MFMA on ALL that wave's a1-loads (rows
// [base,base+32)), and waves touch disjoint row slabs. P has no aliases.
__global__ void __launch_bounds__(256) k_fuse4(const bf16_t* __restrict__ xbf,
                                               const bf16_t* __restrict__ W3rr,
                                               bf16_t* __restrict__ P,
                                               const bf16_t* __restrict__ a1,
                                               const bf16_t* __restrict__ W2r,
                                               const float* __restrict__ b2,
                                               bf16_t* __restrict__ h) {
    __shared__ bf16_t sB[16896];   // mlp2 uses [0,16384); pgemm 4x4224
    if (blockIdx.x < 1024) {
        pgemm_body(xbf, W3rr, P, sB, blockIdx.x & 63, blockIdx.x >> 6);
    } else {
        // ---- MLP layer 2: h = gelu(a1 @ W2 + b2), LDS-staged, in-place ----
        int tid = threadIdx.x;
        int wave = tid >> 6, lane = tid & 63, col = lane & 15, quad = lane >> 4;
        int base = (blockIdx.x - 1024) * 128 + wave * 32;
        bf16x8 a[2][8];
#pragma unroll
        for (int t = 0; t < 2; t++) {
            const bf16_t* arow = a1 + (size_t)(base + t * 16 + col) * 256;
#pragma unroll
            for (int kk = 0; kk < 8; kk++)
                a[t][kk] = *(const bf16x8*)(arow + kk * 32 + quad * 8);
        }
#pragma unroll 1
        for (int p = 0; p < 4; p++) {
#pragma unroll
            for (int it = 0; it < 8; it++) {
                int c = it * 256 + tid;
                int fl = c >> 6;
                int e = (c & 63) * 8;
                int kk = fl >> 2, nnl = fl & 3;
                *(bf16x8*)(sB + fl * 512 + e) =
                    *(const bf16x8*)(W2r + (size_t)(kk * 16 + p * 4 + nnl) * 512 + e);
            }
            __syncthreads();
#pragma unroll
            for (int nnl = 0; nnl < 4; nnl++) {
                f32x4 acc0, acc1;
#pragma unroll
                for (int r = 0; r < 4; r++) { acc0[r] = 0.0f; acc1[r] = 0.0f; }
#pragma unroll
                for (int kk = 0; kk < 8; kk++) {
                    bf16x8 b = *(const bf16x8*)(sB + (kk * 4 + nnl) * 512 + lane * 8);
                    acc0 = __builtin_amdgcn_mfma_f32_16x16x32_bf16(a[0][kk], b, acc0, 0, 0, 0);
                    acc1 = __builtin_amdgcn_mfma_f32_16x16x32_bf16(a[1][kk], b, acc1, 0, 0, 0);
                }
                int ncol = (p * 4 + nnl) * 16 + col;
                float bv = b2[ncol];
#pragma unroll
                for (int r = 0; r < 4; r++) {
                    int row0 = base + quad * 4 + r;
                    h[(size_t)row0 * 256 + ncol] = f2bf(gelu_f(acc0[r] + bv));
                    h[(size_t)(row0 + 16) * 256 + ncol] = f2bf(gelu_f(acc1[r] + bv));
                }
            }
            __syncthreads();
        }
    }
}

// ---- standalone P-GEMM for conv 1 ----
__global__ void __launch_bounds__(256) k_pgemm(const bf16_t* __restrict__ xbf,
                                               const bf16_t* __restrict__ W3rr,
                                               bf16_t* __restrict__ P) {
    __shared__ bf16_t sw_all[16896];
    pgemm_body(xbf, W3rr, P, sw_all, blockIdx.x & 63, blockIdx.x >> 6);
}

// ---- aggregation: 32-edge superchunk (same src), 32x32x16 MFMA ----
// A: A[m=lane&31][k=(lane>>5)*8+j]; C/D: col=lane&31, row=(reg&3)+8*(reg>>2)+4*(lane>>5)
// P chunks are channel-rotated: phys chunk = (logical + 5*v) & 31 (see pgemm).
__global__ void __launch_bounds__(256) k_agg(const int4* __restrict__ descs,
                                             const int2* __restrict__ sorted,
                                             const bf16_t* __restrict__ h,
                                             const bf16_t* __restrict__ P,
                                             const float* __restrict__ Q,
                                             float* __restrict__ agg) {
    int chunk = blockIdx.x * 4 + (threadIdx.x >> 6);
    int lane = threadIdx.x & 63;
    int row = lane & 31, khalf = lane >> 5;
    int4 d = descs[chunk];
    int v = d.x, base = d.y, cnt = d.z;
    if (cnt == 0) return;
    bool valid = (row < cnt);
    int2 ed = sorted[base + (valid ? row : 0)];
    int eid = ed.x, dst = ed.y;

    bf16x8 zero;
#pragma unroll
    for (int i = 0; i < 8; i++) zero[i] = (bf16_t)0.0f;

    bf16x8 a[16];
    const bf16_t* hrow = h + (size_t)eid * 256;
#pragma unroll
    for (int kt = 0; kt < 16; kt++) {
        bf16x8 t = *(const bf16x8*)(hrow + kt * 16 + khalf * 8);
        a[kt] = valid ? t : zero;
    }
    const bf16_t* Pv = P + (size_t)v * 16384;
    int rot = v * 5;
    f32x16 acc0, acc1;
#pragma unroll
    for (int r = 0; r < 16; r++) { acc0[r] = 0.0f; acc1[r] = 0.0f; }
#pragma unroll
    for (int kt = 0; kt < 16; kt++) {
        int c0 = (kt * 2 + 0 + rot) & 31;
        int c1 = (kt * 2 + 1 + rot) & 31;
        bf16x8 b0 = *(const bf16x8*)(Pv + c0 * 512 + lane * 8);
        bf16x8 b1 = *(const bf16x8*)(Pv + c1 * 512 + lane * 8);
        acc0 = __builtin_amdgcn_mfma_f32_32x32x16_bf16(a[kt], b0, acc0, 0, 0, 0);
        acc1 = __builtin_amdgcn_mfma_f32_32x32x16_bf16(a[kt], b1, acc1, 0, 0, 0);
    }
    float q0 = Q[v * 64 + row];
    float q1 = Q[v * 64 + 32 + row];
#pragma unroll
    for (int r = 0; r < 16; r++) {
        int mm = (r & 3) + 8 * (r >> 2) + 4 * khalf;
        int de = __shfl(dst, mm, 64);
        if (mm < cnt) {
            atomicAdd(&agg[(size_t)de * 64 + row], acc0[r] + q0);
            atomicAdd(&agg[(size_t)de * 64 + 32 + row], acc1[r] + q1);
        }
    }
}

// ---- combine after conv0: x1 = gelu(agg + x@Wroot + bias); also x1bf, Q1 ----
__global__ void k_combine1(const float* __restrict__ x, const float* __restrict__ agg,
                           const float* __restrict__ Wroot, const float* __restrict__ bias,
                           const float* __restrict__ b3, float* __restrict__ x1,
                           bf16_t* __restrict__ x1bf, float* __restrict__ Q1) {
    __shared__ float sx[64], sy[64];
    int v = blockIdx.x, o = threadIdx.x;
    sx[o] = x[v * 64 + o];
    __syncthreads();
    float acc = agg[v * 64 + o] + bias[o];
#pragma unroll 8
    for (int i = 0; i < 64; i++) acc += sx[i] * Wroot[i * 64 + o];
    acc = gelu_f(acc);
    x1[v * 64 + o] = acc;
    x1bf[v * 64 + o] = f2bf(acc);
    sy[o] = acc;
    __syncthreads();
    float q = 0.0f;
#pragma unroll 8
    for (int i = 0; i < 64; i++) q += sy[i] * b3[i * 64 + o];
    Q1[v * 64 + o] = q;
}

// ---- final combine: out = agg + x1@Wroot + bias ----
__global__ void k_combine2(const float* __restrict__ x1, const float* __restrict__ agg,
                           const float* __restrict__ Wroot, const float* __restrict__ bias,
                           float* __restrict__ out) {
    __shared__ float sx[64];
    int v = blockIdx.x, o = threadIdx.x;
    sx[o] = x1[v * 64 + o];
    __syncthreads();
    float acc = agg[v * 64 + o] + bias[o];
#pragma unroll 8
    for (int i = 0; i < 64; i++) acc += sx[i] * Wroot[i * 64 + o];
    out[v * 64 + o] = acc;
}

extern "C" void kernel_launch(void* const* d_in, const int* in_sizes, int n_in,
                              void* d_out, int out_size, void* d_ws, size_t ws_size,
                              hipStream_t stream) {
    const float* nodes = (const float*)d_in[0];
    const int*   ei    = (const int*)d_in[1];
    const float* attr  = (const float*)d_in[2];
    const float* W1    = (const float*)d_in[3];
    const float* b1    = (const float*)d_in[4];
    const float* W2    = (const float*)d_in[5];
    const float* b2    = (const float*)d_in[6];
    const float* W3    = (const float*)d_in[7];
    const float* b3    = (const float*)d_in[8];
    const float* Wroot = (const float*)d_in[9];
    const float* bias  = (const float*)d_in[10];
    float* out = (float*)d_out;
    char* ws = (char*)d_ws;

    int*    cnt    = (int*)(ws + OFF_CNT);
    int4*   descs  = (int4*)(ws + OFF_DESC);
    float*  agg0   = (float*)(ws + OFF_AGG0);
    float*  agg1   = (float*)(ws + OFF_AGG1);
    int*    cursor = (int*)(ws + OFF_CURSOR);
    int2*   sorted = (int2*)(ws + OFF_SORTED);
    bf16_t* W2r    = (bf16_t*)(ws + OFF_W2R);
    bf16_t* W3rr   = (bf16_t*)(ws + OFF_W3RR);
    float*  Q0     = (float*)(ws + OFF_Q0);
    float*  Q1     = (float*)(ws + OFF_Q1);
    float*  x1f    = (float*)(ws + OFF_X1F);
    bf16_t* x0bf   = (bf16_t*)(ws + OFF_X0BF);
    bf16_t* x1bf   = (bf16_t*)(ws + OFF_X1BF);
    bf16_t* hbuf   = (bf16_t*)(ws + OFF_H);
    bf16_t* a1buf  = (bf16_t*)(ws + OFF_H);  // alias: mlp2 is an in-place slab transform
    bf16_t* Pbuf   = (bf16_t*)(ws + OFF_P);  // no aliases

    hipMemsetAsync(ws, 0, ZERO_BYTES, stream);
    k_hist<<<NE / 256, 256, 0, stream>>>(ei, cnt);
    k_scan<<<1, 1024, 0, stream>>>(cnt, cursor, descs);
    k_fuse3<<<2816, 256, 0, stream>>>(ei, cursor, sorted, W3, W3rr, W2, W2r,
                                      attr, W1, b1, a1buf, nodes, b3, x0bf, Q0);
    k_fuse4<<<1536, 256, 0, stream>>>(x0bf, W3rr, Pbuf, a1buf, W2r, b2, hbuf);
    // conv 0
    k_agg<<<MAXSUPER / 4, 256, 0, stream>>>(descs, sorted, hbuf, Pbuf, Q0, agg0);
    k_combine1<<<NN, 64, 0, stream>>>(nodes, agg0, Wroot, bias, b3, x1f, x1bf, Q1);
    // conv 1
    k_pgemm<<<1024, 256, 0, stream>>>(x1bf, W3rr, Pbuf);
    k_agg<<<MAXSUPER / 4, 256, 0, stream>>>(descs, sorted, hbuf, Pbuf, Q1, agg1);
    k_combine2<<<NN, 64, 0, stream>>>(x1f, agg1, Wroot, bias, out);
}